// Round 2
// baseline (483.650 us; speedup 1.0000x reference)
//
#include <hip/hip_runtime.h>
#include <cstddef>

#define NN 256          // nodes
#define VD 64           // V
#define ED 64           // E
#define SD 16           // S
#define HD 16           // H
#define EPS 65280       // edges per s = N*(N-1)

__device__ __forceinline__ float fast_tanh(float x) {
    // tanh(x) = 1 - 2/(exp(2x)+1); exp via v_exp_f32, rcp via v_rcp_f32.
    float e = __expf(2.0f * x);
    float r = __builtin_amdgcn_rcpf(e + 1.0f);
    return 1.0f - 2.0f * r;
}

// ---------------- Kernel P: per-node first-layer tables ----------------
// Tables are written into the dv_out region of the OUTPUT buffer (512 KB of
// the 1 MB dv region) so the workspace d_ws is never touched. dv_kernel runs
// last and overwrites the region with final dv values.
__global__ __launch_bounds__(256) void precompute_ab(
    const float* __restrict__ v0, const float* __restrict__ we1,
    float* __restrict__ a_tab, float* __restrict__ b_tab) {
    int t = threadIdx.x;
    int i = t & 15;
    int nl = t >> 4;
    int node = blockIdx.x * 16 + nl;          // s*256+n, 0..4095
    const float* vrow = v0 + (size_t)node * VD;
    float a = 0.f, b = 0.f;
    #pragma unroll
    for (int k = 0; k < VD; ++k) {
        float x = vrow[k];
        a += x * we1[k * HD + i];
        b += x * we1[(VD + k) * HD + i];
    }
    a_tab[node * HD + i] = a;
    b_tab[node * HD + i] = b;
}

// ---------------- Kernel B: de = tanh(a[recv]+b[send]+be1) @ we2 + be2 ----------------
__global__ __launch_bounds__(256) void de_kernel(
    const float* __restrict__ a_tab, const float* __restrict__ b_tab,
    const float* __restrict__ we2, const float* __restrict__ be1,
    const float* __restrict__ be2,
    const int* __restrict__ recv_idx, const int* __restrict__ send_idx,
    float* __restrict__ de_out) {
    __shared__ float h_s[64 * 20];            // 5120 B
    int t = threadIdx.x;
    int s = blockIdx.y;
    int tile = blockIdx.x;                    // 0..1019
    int p = t & 63;
    int iq = t >> 6;                          // 0..3
    int eg = tile * 64 + p;                   // edge index within s

    // ---- phase 1: activations ----
    int r  = recv_idx[eg];
    int sd = send_idx[eg];
    const float4 av = *(const float4*)(a_tab + ((s << 8) + r)  * HD + iq * 4);
    const float4 bv = *(const float4*)(b_tab + ((s << 8) + sd) * HD + iq * 4);
    const float4 b1 = *(const float4*)(be1 + iq * 4);
    float4 hv;
    hv.x = fast_tanh(av.x + bv.x + b1.x);
    hv.y = fast_tanh(av.y + bv.y + b1.y);
    hv.z = fast_tanh(av.z + bv.z + b1.z);
    hv.w = fast_tanh(av.w + bv.w + b1.w);
    *(float4*)(h_s + p * 20 + iq * 4) = hv;

    // preload we2 column v and bias (L1-resident across blocks)
    int v = t & 63;
    float w2[16];
    #pragma unroll
    for (int i = 0; i < HD; ++i) w2[i] = we2[i * ED + v];
    float bias = be2[v];
    __syncthreads();

    // ---- phase 2: one wave per edge ----
    int w = t >> 6;                           // wave id, uniform in wave
    size_t outbase = ((size_t)s * EPS + (size_t)tile * 64) * ED;
    for (int pp = w * 16; pp < w * 16 + 16; ++pp) {
        const float* hp = h_s + pp * 20;
        float o = bias;
        #pragma unroll
        for (int i = 0; i < HD; i += 4) {
            float4 h4 = *(const float4*)(hp + i);   // broadcast, conflict-free
            o += h4.x * w2[i] + h4.y * w2[i + 1] + h4.z * w2[i + 2] + h4.w * w2[i + 3];
        }
        de_out[outbase + (size_t)pp * ED + v] = o;  // 256B coalesced per wave
    }
}

// ---------------- Kernel A: ev = sum_j e0[s,n,j,:]; dv = MLP(ev) ----------------
// Runs LAST: overwrites the dv_out region that held a_tab/b_tab.
__global__ __launch_bounds__(256) void dv_kernel(
    const float* __restrict__ e0,
    const float* __restrict__ wv1, const float* __restrict__ bv1,
    const float* __restrict__ wv2, const float* __restrict__ bv2,
    float* __restrict__ dv_out) {
    __shared__ float red[1024];   // 16 groups x 64 e
    __shared__ float ev_s[64];
    __shared__ float h_s[16];
    int t = threadIdx.x;
    int node = blockIdx.x;                    // s*256+n
    const float* base = e0 + (size_t)node * 255 * ED;
    int c = t & 15;                           // float4 column (e/4)
    int g = t >> 4;                           // row group
    float4 acc = make_float4(0.f, 0.f, 0.f, 0.f);
    for (int j = g; j < 255; j += 16) {
        const float4 v = *(const float4*)(base + (size_t)j * ED + c * 4);
        acc.x += v.x; acc.y += v.y; acc.z += v.z; acc.w += v.w;
    }
    *(float4*)(red + g * 64 + c * 4) = acc;
    __syncthreads();
    if (t < 64) {
        float s = 0.f;
        #pragma unroll
        for (int gg = 0; gg < 16; ++gg) s += red[gg * 64 + t];
        ev_s[t] = s;
    }
    __syncthreads();
    if (t < 16) {
        float ah = bv1[t];
        #pragma unroll
        for (int e = 0; e < 64; ++e) ah += ev_s[e] * wv1[e * HD + t];
        h_s[t] = fast_tanh(ah);
    }
    __syncthreads();
    if (t < 64) {
        float o = bv2[t];
        #pragma unroll
        for (int i = 0; i < HD; ++i) o += h_s[i] * wv2[i * VD + t];
        dv_out[(size_t)node * VD + t] = o;
    }
}

extern "C" void kernel_launch(void* const* d_in, const int* in_sizes, int n_in,
                              void* d_out, int out_size, void* d_ws, size_t ws_size,
                              hipStream_t stream) {
    // inputs: t, v0, e0, wv1, bv1, wv2, bv2, we1, be1, we2, be2, recv_idx, send_idx
    const float* v0   = (const float*)d_in[1];
    const float* e0   = (const float*)d_in[2];
    const float* wv1  = (const float*)d_in[3];
    const float* bv1  = (const float*)d_in[4];
    const float* wv2  = (const float*)d_in[5];
    const float* bv2  = (const float*)d_in[6];
    const float* we1  = (const float*)d_in[7];
    const float* be1  = (const float*)d_in[8];
    const float* we2  = (const float*)d_in[9];
    const float* be2  = (const float*)d_in[10];
    const int* recv_idx = (const int*)d_in[11];
    const int* send_idx = (const int*)d_in[12];

    float* dv_out = (float*)d_out;                       // S*N*V = 262144 floats
    float* de_out = dv_out + (size_t)SD * NN * VD;       // S*N*(N-1)*E

    // Scratch tables live in the dv_out region (512 KB of 1 MB); d_ws untouched.
    float* a_tab  = dv_out;                              // 4096*16 floats
    float* b_tab  = dv_out + 4096 * HD;                  // 4096*16 floats
    (void)d_ws; (void)ws_size;

    precompute_ab<<<256, 256, 0, stream>>>(v0, we1, a_tab, b_tab);
    de_kernel<<<dim3(EPS / 64, SD), 256, 0, stream>>>(a_tab, b_tab, we2, be1, be2,
                                                      recv_idx, send_idx, de_out);
    dv_kernel<<<SD * NN, 256, 0, stream>>>(e0, wv1, bv1, wv2, bv2, dv_out);
}

// Round 3
// 453.139 us; speedup vs baseline: 1.0673x; 1.0673x over previous
//
#include <hip/hip_runtime.h>
#include <cstddef>

#define NN 256          // nodes
#define VD 64           // V
#define ED 64           // E
#define SD 16           // S
#define HD 16           // H
#define EPS 65280       // edges per s = N*(N-1)
#define DE_TILES 16320  // SD * EPS/64
#define DV_BLOCKS 4096  // SD * NN

typedef float f32x4 __attribute__((ext_vector_type(4)));

__device__ __forceinline__ float fast_tanh(float x) {
    // tanh(x) = 1 - 2/(exp(2x)+1); exp via v_exp_f32, rcp via v_rcp_f32.
    float e = __expf(2.0f * x);
    float r = __builtin_amdgcn_rcpf(e + 1.0f);
    return 1.0f - 2.0f * r;
}

// ---------------- Kernel P: per-node first-layer tables ----------------
// a[s,n,i] = sum_k v0[s,n,k] * we1[k,i]        (recv half)
// b[s,n,i] = sum_k v0[s,n,k] * we1[64+k,i]     (send half)
__global__ __launch_bounds__(256) void precompute_ab(
    const float* __restrict__ v0, const float* __restrict__ we1,
    float* __restrict__ a_tab, float* __restrict__ b_tab) {
    int t = threadIdx.x;
    int i = t & 15;
    int nl = t >> 4;
    int node = blockIdx.x * 16 + nl;          // s*256+n, 0..4095
    const float* vrow = v0 + (size_t)node * VD;
    float a = 0.f, b = 0.f;
    #pragma unroll
    for (int k = 0; k < VD; ++k) {
        float x = vrow[k];
        a += x * we1[k * HD + i];
        b += x * we1[(VD + k) * HD + i];
    }
    a_tab[node * HD + i] = a;
    b_tab[node * HD + i] = b;
}

// ---------------- Fused kernel: dv blocks and de blocks interleaved ----------------
// Grid = 4096*5 blocks. bid%5==4 -> dv node (read-heavy, streams e0, NT loads).
// bid%5<4  -> de tile (write-heavy, streams de_out, NT stores). Interleave keeps
// both read and write traffic live on HBM simultaneously; NT keeps the two
// touch-once streams from thrashing L2 (tables/weights stay resident).
__global__ __launch_bounds__(256) void fused_dv_de(
    const float* __restrict__ e0,
    const float* __restrict__ wv1, const float* __restrict__ bv1,
    const float* __restrict__ wv2, const float* __restrict__ bv2,
    const float* __restrict__ a_tab, const float* __restrict__ b_tab,
    const float* __restrict__ we2, const float* __restrict__ be1,
    const float* __restrict__ be2,
    const int* __restrict__ recv_idx, const int* __restrict__ send_idx,
    float* __restrict__ dv_out, float* __restrict__ de_out) {
    __shared__ float smem[1344];              // dv: 1024+64+16 | de: 64*20
    int bid = blockIdx.x;
    int q = bid / 5;
    int r = bid - q * 5;                      // block-uniform branch selector
    int t = threadIdx.x;

    if (r == 4) {
        // ---------------- dv path: node = q ----------------
        float* red  = smem;                   // 16 groups x 64 e
        float* ev_s = smem + 1024;
        float* h_s  = smem + 1088;
        int node = q;                         // s*256+n
        const float* base = e0 + (size_t)node * 255 * ED;
        int c = t & 15;                       // float4 column (e/4)
        int g = t >> 4;                       // row group
        f32x4 acc = (f32x4){0.f, 0.f, 0.f, 0.f};
        for (int j = g; j < 255; j += 16) {
            const f32x4 v = __builtin_nontemporal_load(
                (const f32x4*)(base + (size_t)j * ED + c * 4));
            acc += v;
        }
        *(f32x4*)(red + g * 64 + c * 4) = acc;
        __syncthreads();
        if (t < 64) {
            float s = 0.f;
            #pragma unroll
            for (int gg = 0; gg < 16; ++gg) s += red[gg * 64 + t];
            ev_s[t] = s;
        }
        __syncthreads();
        if (t < 16) {
            float ah = bv1[t];
            #pragma unroll
            for (int e = 0; e < 64; ++e) ah += ev_s[e] * wv1[e * HD + t];
            h_s[t] = fast_tanh(ah);
        }
        __syncthreads();
        if (t < 64) {
            float o = bv2[t];
            #pragma unroll
            for (int i = 0; i < HD; ++i) o += h_s[i] * wv2[i * VD + t];
            dv_out[(size_t)node * VD + t] = o;
        }
    } else {
        // ---------------- de path: tile dt = q*4+r ----------------
        int dt = q * 4 + r;
        if (dt >= DE_TILES) return;           // 64 tail blocks idle
        int s = dt / 1020;                    // 1020 tiles per s
        int tile = dt - s * 1020;
        float* h_s = smem;                    // 64 edges x stride 20

        int p = t & 63;
        int iq = t >> 6;                      // 0..3
        int eg = tile * 64 + p;               // edge index within s

        // ---- phase 1: activations ----
        int rr = recv_idx[eg];
        int sd = send_idx[eg];
        const float4 av = *(const float4*)(a_tab + ((s << 8) + rr) * HD + iq * 4);
        const float4 bv = *(const float4*)(b_tab + ((s << 8) + sd) * HD + iq * 4);
        const float4 b1 = *(const float4*)(be1 + iq * 4);
        float4 hv;
        hv.x = fast_tanh(av.x + bv.x + b1.x);
        hv.y = fast_tanh(av.y + bv.y + b1.y);
        hv.z = fast_tanh(av.z + bv.z + b1.z);
        hv.w = fast_tanh(av.w + bv.w + b1.w);
        *(float4*)(h_s + p * 20 + iq * 4) = hv;

        // preload we2 column v and bias (L1-resident across blocks)
        int v = t & 63;
        float w2[16];
        #pragma unroll
        for (int i = 0; i < HD; ++i) w2[i] = we2[i * ED + v];
        float bias = be2[v];
        __syncthreads();

        // ---- phase 2: one wave per edge ----
        int w = t >> 6;                       // wave id, uniform in wave
        size_t outbase = ((size_t)s * EPS + (size_t)tile * 64) * ED;
        for (int pp = w * 16; pp < w * 16 + 16; ++pp) {
            const float* hp = h_s + pp * 20;
            float o = bias;
            #pragma unroll
            for (int i = 0; i < HD; i += 4) {
                float4 h4 = *(const float4*)(hp + i);   // broadcast, conflict-free
                o += h4.x * w2[i] + h4.y * w2[i + 1] + h4.z * w2[i + 2] + h4.w * w2[i + 3];
            }
            // 256B coalesced per wave; NT: bypass L2 (write-once stream)
            __builtin_nontemporal_store(o, de_out + outbase + (size_t)pp * ED + v);
        }
    }
}

extern "C" void kernel_launch(void* const* d_in, const int* in_sizes, int n_in,
                              void* d_out, int out_size, void* d_ws, size_t ws_size,
                              hipStream_t stream) {
    // inputs: t, v0, e0, wv1, bv1, wv2, bv2, we1, be1, we2, be2, recv_idx, send_idx
    const float* v0   = (const float*)d_in[1];
    const float* e0   = (const float*)d_in[2];
    const float* wv1  = (const float*)d_in[3];
    const float* bv1  = (const float*)d_in[4];
    const float* wv2  = (const float*)d_in[5];
    const float* bv2  = (const float*)d_in[6];
    const float* we1  = (const float*)d_in[7];
    const float* be1  = (const float*)d_in[8];
    const float* we2  = (const float*)d_in[9];
    const float* be2  = (const float*)d_in[10];
    const int* recv_idx = (const int*)d_in[11];
    const int* send_idx = (const int*)d_in[12];

    float* dv_out = (float*)d_out;                       // S*N*V = 262144 floats
    float* de_out = dv_out + (size_t)SD * NN * VD;       // S*N*(N-1)*E
    float* a_tab  = (float*)d_ws;                        // 4096*16 floats
    float* b_tab  = a_tab + 4096 * HD;                   // 4096*16 floats

    precompute_ab<<<256, 256, 0, stream>>>(v0, we1, a_tab, b_tab);
    fused_dv_de<<<DV_BLOCKS * 5, 256, 0, stream>>>(
        e0, wv1, bv1, wv2, bv2, a_tab, b_tab, we2, be1, be2,
        recv_idx, send_idx, dv_out, de_out);
}